// Round 12
// baseline (65.625 us; speedup 1.0000x reference)
//
#include <hip/hip_runtime.h>

#define HW 262144            // 512*512
#define TSIZE 524288         // 2^19 entries per level
#define HMASK 524287u
#define PRIME2 2654435761u
#define NLEV_LDS 13          // levels 0..12 staged (n <= 73)
#define LDS_TOT 18663        // sum of (NS[l]+2)^2 for l<13, float2 = 149,304 B
#define BLK 1024
#define PPT 2                // pixels per thread

typedef float f2v __attribute__((ext_vector_type(2)));

__device__ __constant__ int c_NS[13]  = {8, 9, 11, 13, 16, 20, 24, 29, 35, 42, 50, 61, 73};
__device__ __constant__ int c_OFF[14] = {0, 100, 221, 390, 615, 939, 1423, 2099, 3060,
                                         4429, 6365, 9069, 13038, 18663};

// Reference semantics (locked R1-R7): JAX/XLA f32:
//   hx = int32(fl32(cx*n)); bx = floorf(fl32(cx*rcp)), rcp = fl32(1/fl32(1/n));
//   NS[15] = 127.
// Ladder: R7 93 -> R8 70 -> R9 67 -> R10 57.7 -> R11 47.9us.
// R11 model: ~86k L1 line-probes/CU (staging 18663 random probes PER BLOCK).
// R12: de-hash ONCE into dense d_ws (18663 probes chip-wide), stage LDS with
// coalesced loads (2333 lines/block). Probes/CU 86k -> ~54k.

// ---- phase 1: de-hash levels 0..12 into dense scratch (run once/launch) ----
__global__ __launch_bounds__(256)
void dehash_kernel(const float* __restrict__ table, float2* __restrict__ dense)
{
    const int e = blockIdx.x * 256 + threadIdx.x;
    if (e >= LDS_TOT) return;
    int l = 0;
    #pragma unroll
    for (int i = 1; i < NLEV_LDS; ++i) l += (e >= c_OFF[i]);
    const int W   = c_NS[l] + 2;
    const int rel = e - c_OFF[l];
    const int j   = rel / W;
    const int i2  = rel - j * W;
    const unsigned idx = ((unsigned)i2 ^ ((unsigned)j * PRIME2)) & HMASK;
    dense[e] = reinterpret_cast<const float2*>(table)[(size_t)l * TSIZE + idx];
}

// ---- phase 2: fused encode. DENSE=true: stage LDS from dense scratch
//      (coalesced); DENSE=false: in-kernel de-hash (R11 fallback). ----
template <bool DENSE>
__global__ __launch_bounds__(BLK)
void hashenc_fused(const float* __restrict__ coord,
                   const float* __restrict__ table,
                   const float2* __restrict__ dense,
                   float* __restrict__ out)
{
    constexpr int NS[13]  = {8, 9, 11, 13, 16, 20, 24, 29, 35, 42, 50, 61, 73};
    constexpr int OFF[13] = {0, 100, 221, 390, 615, 939, 1423, 2099, 3060, 4429,
                             6365, 9069, 13038};
    constexpr int NSD[3]  = {88, 106, 127};   // direct levels 13,14,15

    extern __shared__ float2 smem[];   // 18663 float2 = 149,304 B

    const float2* __restrict__ tab2 = reinterpret_cast<const float2*>(table);

    // ---- per-thread pixel pair ----
    const int g   = blockIdx.x * BLK + threadIdx.x;   // 0..524287
    const int P   = g << 1;
    const int b   = P >> 18;                          // batch (HW = 2^18)
    const int pos = P & (HW - 1);

    const float* cbase = coord + (size_t)b * (2 * HW);
    const float2 cxp = *reinterpret_cast<const float2*>(cbase + pos);
    const float2 cyp = *reinterpret_cast<const float2*>(cbase + HW + pos);
    const float cxa[PPT] = {cxp.x, cxp.y};
    const float cya[PPT] = {cyp.x, cyp.y};

    float* outb = out + (size_t)b * (32 * HW) + pos;

    // ---- issue direct-level gathers FIRST: in flight through staging ----
    float2 gd[3][PPT * 4];
    #pragma unroll
    for (int k = 0; k < 3; ++k) {
        const float n = (float)NSD[k];
        const float2* __restrict__ tabl = tab2 + (size_t)(13 + k) * TSIZE;
        #pragma unroll
        for (int p = 0; p < PPT; ++p) {
            const int hx = (int)(cxa[p] * n);
            const int hy = (int)(cya[p] * n);
            const unsigned hyp0 = (unsigned)hy * PRIME2;
            const unsigned hyp1 = (unsigned)(hy + 1) * PRIME2;
            gd[k][p * 4 + 0] = tabl[((unsigned)hx       ^ hyp0) & HMASK];
            gd[k][p * 4 + 1] = tabl[((unsigned)(hx + 1) ^ hyp0) & HMASK];
            gd[k][p * 4 + 2] = tabl[((unsigned)hx       ^ hyp1) & HMASK];
            gd[k][p * 4 + 3] = tabl[((unsigned)(hx + 1) ^ hyp1) & HMASK];
        }
    }

    // ---- stage levels 0..12 into LDS ----
    if (DENSE) {
        for (int e = threadIdx.x; e < LDS_TOT; e += BLK)
            smem[e] = dense[e];                    // coalesced 8B loads
    } else {
        #pragma unroll
        for (int l = 0; l < NLEV_LDS; ++l) {
            const int W  = NS[l] + 2;
            const int SZ = W * W;
            const float2* __restrict__ tabl = tab2 + (size_t)l * TSIZE;
            for (int e = threadIdx.x; e < SZ; e += BLK) {
                const int j = e / W;
                const int i = e - j * W;
                const unsigned idx = ((unsigned)i ^ ((unsigned)j * PRIME2)) & HMASK;
                smem[OFF[l] + e] = tabl[idx];
            }
        }
    }

    __syncthreads();

    // ---- staged levels 0..12 from LDS ----
    #pragma unroll
    for (int l = 0; l < NLEV_LDS; ++l) {
        const float n   = (float)NS[l];
        const float inv = 1.0f / n;
        const float rcp = 1.0f / inv;
        const int   W   = NS[l] + 2;
        const float2* __restrict__ sl = smem + OFF[l];

        float o0[PPT], o1[PPT];
        #pragma unroll
        for (int p = 0; p < PPT; ++p) {
            const float cx = cxa[p], cy = cya[p];
            const int hx = (int)(cx * n);
            const int hy = (int)(cy * n);
            const float bx = floorf(cx * rcp);
            const float by = floorf(cy * rcp);

            const int base = hy * W + hx;
            const float2 f00 = sl[base];
            const float2 f10 = sl[base + 1];
            const float2 f01 = sl[base + W];
            const float2 f11 = sl[base + W + 1];

            const float wx_lo = ((bx + 1.0f) * inv - cx) * n;
            const float wx_hi = (cx - bx * inv) * n;
            const float wy_lo = ((by + 1.0f) * inv - cy) * n;
            const float wy_hi = (cy - by * inv) * n;

            const float r1x = f00.x * wx_lo + f10.x * wx_hi;
            const float r1y = f00.y * wx_lo + f10.y * wx_hi;
            const float r2x = f01.x * wx_lo + f11.x * wx_hi;
            const float r2y = f01.y * wx_lo + f11.y * wx_hi;
            o0[p] = r1x * wy_lo + r2x * wy_hi;
            o1[p] = r1y * wy_lo + r2y * wy_hi;
        }
        f2v v0 = {o0[0], o0[1]};
        f2v v1 = {o1[0], o1[1]};
        __builtin_nontemporal_store(v0, (f2v*)(outb + (size_t)(2 * l)     * HW));
        __builtin_nontemporal_store(v1, (f2v*)(outb + (size_t)(2 * l + 1) * HW));
    }

    // ---- direct levels 13..15: blend the landed gathers ----
    #pragma unroll
    for (int k = 0; k < 3; ++k) {
        const int   l   = 13 + k;
        const float n   = (float)NSD[k];
        const float inv = 1.0f / n;
        const float rcp = 1.0f / inv;

        float o0[PPT], o1[PPT];
        #pragma unroll
        for (int p = 0; p < PPT; ++p) {
            const float cx = cxa[p], cy = cya[p];
            const float bx = floorf(cx * rcp);
            const float by = floorf(cy * rcp);

            const float2 f00 = gd[k][p * 4 + 0];
            const float2 f10 = gd[k][p * 4 + 1];
            const float2 f01 = gd[k][p * 4 + 2];
            const float2 f11 = gd[k][p * 4 + 3];

            const float wx_lo = ((bx + 1.0f) * inv - cx) * n;
            const float wx_hi = (cx - bx * inv) * n;
            const float wy_lo = ((by + 1.0f) * inv - cy) * n;
            const float wy_hi = (cy - by * inv) * n;

            const float r1x = f00.x * wx_lo + f10.x * wx_hi;
            const float r1y = f00.y * wx_lo + f10.y * wx_hi;
            const float r2x = f01.x * wx_lo + f11.x * wx_hi;
            const float r2y = f01.y * wx_lo + f11.y * wx_hi;
            o0[p] = r1x * wy_lo + r2x * wy_hi;
            o1[p] = r1y * wy_lo + r2y * wy_hi;
        }
        f2v v0 = {o0[0], o0[1]};
        f2v v1 = {o1[0], o1[1]};
        __builtin_nontemporal_store(v0, (f2v*)(outb + (size_t)(2 * l)     * HW));
        __builtin_nontemporal_store(v1, (f2v*)(outb + (size_t)(2 * l + 1) * HW));
    }
}

extern "C" void kernel_launch(void* const* d_in, const int* in_sizes, int n_in,
                              void* d_out, int out_size, void* d_ws, size_t ws_size,
                              hipStream_t stream) {
    const float* coord = (const float*)d_in[0];
    const float* table = (const float*)d_in[1];
    if (n_in >= 2 && in_sizes[0] > in_sizes[1]) {   // size-based disambiguation
        coord = (const float*)d_in[1];
        table = (const float*)d_in[0];
    }
    float* out = (float*)d_out;
    const size_t need = (size_t)LDS_TOT * sizeof(float2);

    if (ws_size >= need && d_ws != nullptr) {
        float2* dense = (float2*)d_ws;
        (void)hipFuncSetAttribute((const void*)hashenc_fused<true>,
                                  hipFuncAttributeMaxDynamicSharedMemorySize,
                                  (int)need);
        // phase 1: de-hash 18663 entries once (73 blocks x 256)
        dehash_kernel<<<(LDS_TOT + 255) / 256, 256, 0, stream>>>(table, dense);
        // phase 2: 1M px / (1024 thr * 2 px) = 512 blocks, 149KB LDS
        hashenc_fused<true><<<512, BLK, need, stream>>>(coord, table, dense, out);
    } else {
        (void)hipFuncSetAttribute((const void*)hashenc_fused<false>,
                                  hipFuncAttributeMaxDynamicSharedMemorySize,
                                  (int)need);
        hashenc_fused<false><<<512, BLK, need, stream>>>(coord, table, nullptr, out);
    }
}

// Round 13
// 51.350 us; speedup vs baseline: 1.2780x; 1.2780x over previous
//
#include <hip/hip_runtime.h>

#define HW 262144            // 512*512
#define TSIZE 524288         // 2^19 entries per level
#define HMASK 524287u
#define PRIME2 2654435761u
#define NLEV_LDS 13          // levels 0..12 staged (n <= 73)
#define STG_TOT 18663        // sum of (NS[l]+2)^2 for l<13 (float2)
#define DUP_TOT 36405        // 90^2 + 108^2 + 129^2 (float4 pairs, levels 13..15)
#define DUP_F4_OFF 9332      // STG_TOT float2 = 149,304 B -> pad to 149,312 = 9332 float4
#define WS_NEED (149312 + 582480)
#define BLK 1024
#define PPT 2                // pixels per thread

typedef float f2v __attribute__((ext_vector_type(2)));

__device__ __constant__ int c_NS[13]  = {8, 9, 11, 13, 16, 20, 24, 29, 35, 42, 50, 61, 73};
__device__ __constant__ int c_OFF[14] = {0, 100, 221, 390, 615, 939, 1423, 2099, 3060,
                                         4429, 6365, 9069, 13038, 18663};

// Reference semantics (locked R1-R7): JAX/XLA f32:
//   hx = int32(fl32(cx*n)); bx = floorf(fl32(cx*rcp)), rcp = fl32(1/fl32(1/n));
//   NS[15] = 127.
// Ladder: R7 93 -> R8 70 -> R9 67 -> R10 57.7 -> R11 47.9 -> R12 65.6 (REGRESSION:
// gathers issued BEFORE staging; FIFO vmcnt made every ds_write drain them ->
// gather cost serialized with VALU phase instead of overlapping).
// R13: R11 ordering restored + dense coalesced staging + paired-dup float4
// layout for direct levels (4 corner loads -> 2 aligned float4 loads).

// ---- phase 1: build dense scratch (staged grids + paired-dup direct grids) ----
__global__ __launch_bounds__(256)
void dehash_kernel(const float* __restrict__ table, float2* __restrict__ ws2)
{
    const int e = blockIdx.x * 256 + threadIdx.x;
    const float2* __restrict__ tab2 = reinterpret_cast<const float2*>(table);

    if (e < STG_TOT) {
        int l = 0;
        #pragma unroll
        for (int i = 1; i < NLEV_LDS; ++i) l += (e >= c_OFF[i]);
        const int W   = c_NS[l] + 2;
        const int rel = e - c_OFF[l];
        const int j   = rel / W;
        const int i2  = rel - j * W;
        const unsigned idx = ((unsigned)i2 ^ ((unsigned)j * PRIME2)) & HMASK;
        ws2[e] = tab2[(size_t)l * TSIZE + idx];
    } else if (e < STG_TOT + DUP_TOT) {
        const int e2 = e - STG_TOT;
        int k, W, rel;
        if (e2 < 8100)       { k = 0; W = 90;  rel = e2; }
        else if (e2 < 19764) { k = 1; W = 108; rel = e2 - 8100; }
        else                 { k = 2; W = 129; rel = e2 - 19764; }
        const int j  = rel / W;
        const int i2 = rel - j * W;
        const float2* __restrict__ tabl = tab2 + (size_t)(13 + k) * TSIZE;
        const unsigned jp = (unsigned)j * PRIME2;
        const float2 a = tabl[((unsigned)i2       ^ jp) & HMASK];
        const float2 b = tabl[((unsigned)(i2 + 1) ^ jp) & HMASK];
        float4* __restrict__ dup = reinterpret_cast<float4*>(ws2) + DUP_F4_OFF;
        dup[e2] = make_float4(a.x, a.y, b.x, b.y);
    }
}

// ---- phase 2: fused encode. DENSE: stage from scratch + dup direct loads.
//      Fallback (!DENSE): R11 in-kernel de-hash + 4-way direct loads. ----
template <bool DENSE>
__global__ __launch_bounds__(BLK)
void hashenc_fused(const float* __restrict__ coord,
                   const float* __restrict__ table,
                   const float2* __restrict__ ws2,
                   float* __restrict__ out)
{
    constexpr int NS[13]  = {8, 9, 11, 13, 16, 20, 24, 29, 35, 42, 50, 61, 73};
    constexpr int OFF[13] = {0, 100, 221, 390, 615, 939, 1423, 2099, 3060, 4429,
                             6365, 9069, 13038};
    constexpr int NSD[3]  = {88, 106, 127};   // direct levels 13,14,15
    constexpr int WD[3]   = {90, 108, 129};
    constexpr int DOFF[3] = {0, 8100, 19764};

    extern __shared__ float2 smem[];   // 18663 float2 = 149,304 B

    const float2* __restrict__ tab2 = reinterpret_cast<const float2*>(table);

    // ---- stage levels 0..12 into LDS (FIRST: only pre-barrier vmcnt ops) ----
    if (DENSE) {
        for (int e = threadIdx.x; e < STG_TOT; e += BLK)
            smem[e] = ws2[e];                      // coalesced 8B loads
    } else {
        #pragma unroll
        for (int l = 0; l < NLEV_LDS; ++l) {
            const int W  = NS[l] + 2;
            const int SZ = W * W;
            const float2* __restrict__ tabl = tab2 + (size_t)l * TSIZE;
            for (int e = threadIdx.x; e < SZ; e += BLK) {
                const int j = e / W;
                const int i = e - j * W;
                const unsigned idx = ((unsigned)i ^ ((unsigned)j * PRIME2)) & HMASK;
                smem[OFF[l] + e] = tabl[idx];
            }
        }
    }

    // ---- per-thread pixel pair ----
    const int g   = blockIdx.x * BLK + threadIdx.x;   // 0..524287
    const int P   = g << 1;
    const int b   = P >> 18;                          // batch (HW = 2^18)
    const int pos = P & (HW - 1);

    const float* cbase = coord + (size_t)b * (2 * HW);
    const float2 cxp = *reinterpret_cast<const float2*>(cbase + pos);
    const float2 cyp = *reinterpret_cast<const float2*>(cbase + HW + pos);
    const float cxa[PPT] = {cxp.x, cxp.y};
    const float cya[PPT] = {cyp.x, cyp.y};

    float* outb = out + (size_t)b * (32 * HW) + pos;

    __syncthreads();

    // ---- issue direct-level gathers NOW (post-barrier): latency hides
    //      under the LDS-level VALU work below ----
    float4 qd[3][PPT * 2];     // DENSE path: (f00,f10) and (f01,f11) pairs
    float2 gd[3][PPT * 4];     // fallback path
    if (DENSE) {
        const float4* __restrict__ dup =
            reinterpret_cast<const float4*>(ws2) + DUP_F4_OFF;
        #pragma unroll
        for (int k = 0; k < 3; ++k) {
            const float n = (float)NSD[k];
            const float4* __restrict__ dl = dup + DOFF[k];
            #pragma unroll
            for (int p = 0; p < PPT; ++p) {
                const int hx = (int)(cxa[p] * n);
                const int hy = (int)(cya[p] * n);
                const int base = hy * WD[k] + hx;
                qd[k][p * 2 + 0] = dl[base];           // f00 | f10
                qd[k][p * 2 + 1] = dl[base + WD[k]];   // f01 | f11
            }
        }
    } else {
        #pragma unroll
        for (int k = 0; k < 3; ++k) {
            const float n = (float)NSD[k];
            const float2* __restrict__ tabl = tab2 + (size_t)(13 + k) * TSIZE;
            #pragma unroll
            for (int p = 0; p < PPT; ++p) {
                const int hx = (int)(cxa[p] * n);
                const int hy = (int)(cya[p] * n);
                const unsigned hyp0 = (unsigned)hy * PRIME2;
                const unsigned hyp1 = (unsigned)(hy + 1) * PRIME2;
                gd[k][p * 4 + 0] = tabl[((unsigned)hx       ^ hyp0) & HMASK];
                gd[k][p * 4 + 1] = tabl[((unsigned)(hx + 1) ^ hyp0) & HMASK];
                gd[k][p * 4 + 2] = tabl[((unsigned)hx       ^ hyp1) & HMASK];
                gd[k][p * 4 + 3] = tabl[((unsigned)(hx + 1) ^ hyp1) & HMASK];
            }
        }
    }

    // ---- staged levels 0..12 from LDS (lgkmcnt pipe; gathers in flight) ----
    #pragma unroll
    for (int l = 0; l < NLEV_LDS; ++l) {
        const float n   = (float)NS[l];
        const float inv = 1.0f / n;
        const float rcp = 1.0f / inv;
        const int   W   = NS[l] + 2;
        const float2* __restrict__ sl = smem + OFF[l];

        float o0[PPT], o1[PPT];
        #pragma unroll
        for (int p = 0; p < PPT; ++p) {
            const float cx = cxa[p], cy = cya[p];
            const int hx = (int)(cx * n);
            const int hy = (int)(cy * n);
            const float bx = floorf(cx * rcp);
            const float by = floorf(cy * rcp);

            const int base = hy * W + hx;
            const float2 f00 = sl[base];
            const float2 f10 = sl[base + 1];
            const float2 f01 = sl[base + W];
            const float2 f11 = sl[base + W + 1];

            const float wx_lo = ((bx + 1.0f) * inv - cx) * n;
            const float wx_hi = (cx - bx * inv) * n;
            const float wy_lo = ((by + 1.0f) * inv - cy) * n;
            const float wy_hi = (cy - by * inv) * n;

            const float r1x = f00.x * wx_lo + f10.x * wx_hi;
            const float r1y = f00.y * wx_lo + f10.y * wx_hi;
            const float r2x = f01.x * wx_lo + f11.x * wx_hi;
            const float r2y = f01.y * wx_lo + f11.y * wx_hi;
            o0[p] = r1x * wy_lo + r2x * wy_hi;
            o1[p] = r1y * wy_lo + r2y * wy_hi;
        }
        f2v v0 = {o0[0], o0[1]};
        f2v v1 = {o1[0], o1[1]};
        __builtin_nontemporal_store(v0, (f2v*)(outb + (size_t)(2 * l)     * HW));
        __builtin_nontemporal_store(v1, (f2v*)(outb + (size_t)(2 * l + 1) * HW));
    }

    // ---- direct levels 13..15: blend the landed gathers ----
    #pragma unroll
    for (int k = 0; k < 3; ++k) {
        const int   l   = 13 + k;
        const float n   = (float)NSD[k];
        const float inv = 1.0f / n;
        const float rcp = 1.0f / inv;

        float o0[PPT], o1[PPT];
        #pragma unroll
        for (int p = 0; p < PPT; ++p) {
            const float cx = cxa[p], cy = cya[p];
            const float bx = floorf(cx * rcp);
            const float by = floorf(cy * rcp);

            float2 f00, f10, f01, f11;
            if (DENSE) {
                const float4 q0 = qd[k][p * 2 + 0];
                const float4 q1 = qd[k][p * 2 + 1];
                f00 = make_float2(q0.x, q0.y);
                f10 = make_float2(q0.z, q0.w);
                f01 = make_float2(q1.x, q1.y);
                f11 = make_float2(q1.z, q1.w);
            } else {
                f00 = gd[k][p * 4 + 0];
                f10 = gd[k][p * 4 + 1];
                f01 = gd[k][p * 4 + 2];
                f11 = gd[k][p * 4 + 3];
            }

            const float wx_lo = ((bx + 1.0f) * inv - cx) * n;
            const float wx_hi = (cx - bx * inv) * n;
            const float wy_lo = ((by + 1.0f) * inv - cy) * n;
            const float wy_hi = (cy - by * inv) * n;

            const float r1x = f00.x * wx_lo + f10.x * wx_hi;
            const float r1y = f00.y * wx_lo + f10.y * wx_hi;
            const float r2x = f01.x * wx_lo + f11.x * wx_hi;
            const float r2y = f01.y * wx_lo + f11.y * wx_hi;
            o0[p] = r1x * wy_lo + r2x * wy_hi;
            o1[p] = r1y * wy_lo + r2y * wy_hi;
        }
        f2v v0 = {o0[0], o0[1]};
        f2v v1 = {o1[0], o1[1]};
        __builtin_nontemporal_store(v0, (f2v*)(outb + (size_t)(2 * l)     * HW));
        __builtin_nontemporal_store(v1, (f2v*)(outb + (size_t)(2 * l + 1) * HW));
    }
}

extern "C" void kernel_launch(void* const* d_in, const int* in_sizes, int n_in,
                              void* d_out, int out_size, void* d_ws, size_t ws_size,
                              hipStream_t stream) {
    const float* coord = (const float*)d_in[0];
    const float* table = (const float*)d_in[1];
    if (n_in >= 2 && in_sizes[0] > in_sizes[1]) {   // size-based disambiguation
        coord = (const float*)d_in[1];
        table = (const float*)d_in[0];
    }
    float* out = (float*)d_out;
    const int lds_bytes = STG_TOT * (int)sizeof(float2);   // 149,304 B

    if (ws_size >= (size_t)WS_NEED && d_ws != nullptr) {
        float2* ws2 = (float2*)d_ws;
        (void)hipFuncSetAttribute((const void*)hashenc_fused<true>,
                                  hipFuncAttributeMaxDynamicSharedMemorySize,
                                  lds_bytes);
        // phase 1: 18663 staged + 36405 dup entries = 55068 -> 216 blocks
        dehash_kernel<<<(STG_TOT + DUP_TOT + 255) / 256, 256, 0, stream>>>(table, ws2);
        // phase 2: 1M px / (1024 thr * 2 px) = 512 blocks, 149KB LDS
        hashenc_fused<true><<<512, BLK, lds_bytes, stream>>>(coord, table, ws2, out);
    } else {
        (void)hipFuncSetAttribute((const void*)hashenc_fused<false>,
                                  hipFuncAttributeMaxDynamicSharedMemorySize,
                                  lds_bytes);
        hashenc_fused<false><<<512, BLK, lds_bytes, stream>>>(coord, table, nullptr, out);
    }
}